// Round 3
// baseline (597.083 us; speedup 1.0000x reference)
//
#include <hip/hip_runtime.h>
#include <math.h>

#define HIDDEN 1024
#define SEQ    4096
#define BATCH  4

typedef _Float16 f16x8 __attribute__((ext_vector_type(8)));
typedef float    floatx4 __attribute__((ext_vector_type(4)));

// async 16B global->LDS copy (m97: width=16 emits global_load_lds_dwordx4)
__device__ inline void gld16(const void* g, void* l) {
    __builtin_amdgcn_global_load_lds(
        (const __attribute__((address_space(1))) unsigned int*)g,
        (__attribute__((address_space(3))) unsigned int*)l, 16, 0, 0);
}

// ===========================================================================
// 128x128-tile kernel, 256 thr = 4 waves (2x2), wave tile 64x64.
// MODE 5: fused QKV projection. grid (24,128,1). A=Xh [16384,1024].
//         which = col0>>10 picks Wq/Wk/Wv; which<2 -> Qo/Ko[r*1024+cl];
//         which==2 -> Vt[(b*1024+cl)*4096+s].
// ===========================================================================
template<int MODE>
__global__ __launch_bounds__(256)
void gemm128_kernel(const _Float16* __restrict__ A,
                    const _Float16* __restrict__ Bq,
                    const _Float16* __restrict__ Bk,
                    const _Float16* __restrict__ Bv,
                    const float* __restrict__ bq,
                    const float* __restrict__ bk,
                    const float* __restrict__ bv,
                    float alpha,
                    _Float16* __restrict__ Eo,
                    _Float16* __restrict__ Qo,
                    _Float16* __restrict__ Ko,
                    _Float16* __restrict__ Vo,
                    float* __restrict__ Lsum,
                    int K, int lda, int ldb) {
    __shared__ __align__(16) char smem[16384];
    char* sA = smem;          // 8 KB: 128 rows x 32 f16, swizzled 16B chunks
    char* sB = smem + 8192;

    const int tid  = threadIdx.x;
    const int lane = tid & 63;
    const int w    = tid >> 6;
    const int wm   = w & 1;
    const int wn   = w >> 1;
    const int quad = lane >> 4;
    const int l16  = lane & 15;
    const int swz  = (l16 >> 1) & 3;

    int row0, col0;
    if (MODE == 5) {
        // XCD swizzle: n%8 = XCD (round-robin dispatch assumption).
        const int n    = blockIdx.x + 24 * blockIdx.y;
        const int xcd  = n & 7;
        const int slot = n >> 3;                 // 0..383
        const int cc   = slot % 24;
        const int rg   = xcd + 8 * (slot / 24);  // 0..127
        row0 = rg * 128;
        col0 = cc * 128;
    } else {
        row0 = blockIdx.y * 128;
        col0 = blockIdx.x * 128;
    }
    const int bz = blockIdx.z;

    if (MODE == 3) {
        A    += (size_t)bz * SEQ * HIDDEN;
        Bq   += (size_t)bz * SEQ * HIDDEN;
        Eo   += (size_t)bz * SEQ * SEQ;
        Lsum += (size_t)bz * SEQ;
    }

    const _Float16* Bsrc = Bq;
    int colbase = col0;
    int which = 0;
    if (MODE == 5) {
        which = col0 >> 10;
        Bsrc = (which == 0) ? Bq : (which == 1) ? Bk : Bv;
        colbase = col0 & 1023;
    }

    floatx4 acc[4][4];
    #pragma unroll
    for (int i = 0; i < 4; ++i)
        #pragma unroll
        for (int j = 0; j < 4; ++j) acc[i][j] = (floatx4){0.f, 0.f, 0.f, 0.f};

    const f16x8* pA = (const f16x8*)sA;
    const f16x8* pB = (const f16x8*)sB;

    int srow[2], scol[2];
    #pragma unroll
    for (int it = 0; it < 2; ++it) {
        const int n = tid + it * 256;
        srow[it] = n >> 2;
        scol[it] = (n & 3) ^ ((srow[it] >> 1) & 3);
    }

    for (int k0 = 0; k0 < K; k0 += 32) {
        #pragma unroll
        for (int it = 0; it < 2; ++it) {
            const int n = tid + it * 256;
            const size_t ga = (size_t)(row0 + srow[it]) * lda + (size_t)k0 + scol[it] * 8;
            const size_t gb = (size_t)(colbase + srow[it]) * ldb + (size_t)k0 + scol[it] * 8;
            gld16(A + ga, sA + n * 16);
            gld16(Bsrc + gb, sB + n * 16);
        }
        __syncthreads();

        f16x8 af[4];
        #pragma unroll
        for (int i = 0; i < 4; ++i) {
            const int r = wm * 64 + i * 16 + l16;
            af[i] = pA[r * 4 + (quad ^ swz)];
        }
        #pragma unroll
        for (int j = 0; j < 4; ++j) {
            const int c = wn * 64 + j * 16 + l16;
            const f16x8 bf = pB[c * 4 + (quad ^ swz)];
            #pragma unroll
            for (int i = 0; i < 4; ++i)
                acc[i][j] = __builtin_amdgcn_mfma_f32_16x16x32_f16(af[i], bf, acc[i][j], 0, 0, 0);
        }
        __syncthreads();
    }

    // ---- epilogue (C/D layout: col=lane&15, row=quad*4+reg) ----
    #pragma unroll
    for (int i = 0; i < 4; ++i) {
        const int r0 = row0 + wm * 64 + i * 16 + quad * 4;
        float rp[4] = {0.f, 0.f, 0.f, 0.f};

        #pragma unroll
        for (int j = 0; j < 4; ++j) {
            const int cl = (MODE == 5 ? colbase : col0) + wn * 64 + j * 16 + l16;

            if (MODE == 5) {
                const float bcol = (which == 0 ? bq : which == 1 ? bk : bv)[cl];
                if (which < 2) {
                    _Float16* O = (which == 0) ? Qo : Ko;
                    #pragma unroll
                    for (int reg = 0; reg < 4; ++reg)
                        O[(size_t)(r0 + reg) * HIDDEN + cl] =
                            (_Float16)(acc[i][j][reg] + bcol);
                } else {
                    const int bb = r0 >> 12;
                    const int s  = r0 & 4095;
                    _Float16 t[4];
                    #pragma unroll
                    for (int reg = 0; reg < 4; ++reg)
                        t[reg] = (_Float16)(acc[i][j][reg] + bcol);
                    *(uint2*)&Vo[((size_t)bb * HIDDEN + cl) * SEQ + s] = *(const uint2*)t;
                }
            } else {  // MODE 3: alpha includes log2e; exp2f -> v_exp_f32
                #pragma unroll
                for (int reg = 0; reg < 4; ++reg) {
                    const float v = exp2f(alpha * acc[i][j][reg] - 5.770780163555856f);
                    const _Float16 vh = (_Float16)v;
                    Eo[(size_t)(r0 + reg) * SEQ + cl] = vh;
                    rp[reg] += (float)vh;
                }
            }
        }

        if (MODE == 3) {
            #pragma unroll
            for (int off = 1; off < 16; off <<= 1)
                #pragma unroll
                for (int reg = 0; reg < 4; ++reg)
                    rp[reg] += __shfl_xor(rp[reg], off, 64);
            if (l16 == 0)
                #pragma unroll
                for (int reg = 0; reg < 4; ++reg)
                    atomicAdd(&Lsum[r0 + reg], rp[reg]);
        }
    }
}

// ===========================================================================
// QK^T kernel: 256x256 tile, BK=64, 512 thr = 8 waves (2M x 4N),
// wave tile 128x64. LDS 128 KB = {A,B} x {2 dbuf} x {2 K-halves} x [256][32]f16.
//
// Fragment double-buffer with read-ahead-1: phase p issues the ds_reads for
// phase p+1 (alternate frag regs), then MFMAs the current frags -> LDS service
// overlaps matrix-pipe backpressure. B-fragments (kh-only) read once per tile.
//
// R3 race fix: counted vmcnt waits go BEFORE the barrier that gates the
// dependent reads (end of p0 / end of p2). vmcnt is PER-WAVE and LDS tiles
// are staged cooperatively by all 8 waves -- a wave's own vmcnt says nothing
// about other waves' staged chunks. wait -> barrier -> read guarantees every
// wave's chunks landed (R2 had barrier -> wait -> read: stale-chunk race).
//
// Phase map (tile T, b=T&1, nb=b^1), steady-state queue 8-10 loads/wave:
//  p0: rd afB<-(RH1,kh0,b)  stage A-kh1(T+1)->nb  MFMA(RH0,afA,bfX)  vm(6)
//  p1: rd afA<-(RH0,kh1,b), bfY<-(kh1,b)
//                           stage B-kh1(T+1)->nb  MFMA(RH1,afB,bfX)
//  p2: rd afB<-(RH1,kh1,b)  stage A-kh0(T+2)->b   MFMA(RH0,afA,bfY)  vm(6)
//  p3: rd afA<-(RH0,kh0,nb), bfX<-(kh0,nb)
//                           stage B-kh0(T+2)->b   MFMA(RH1,afB,bfY)
// Tail waits: tile14 = 6/4, tile15 = 0/none.
// ===========================================================================
__global__ __launch_bounds__(512, 2)
void qk8_kernel(const _Float16* __restrict__ Q,
                const _Float16* __restrict__ Kmat,
                _Float16* __restrict__ E,
                float* __restrict__ Lsum,
                float alpha) {
    __shared__ __align__(16) char smem[131072];
    char* sA = smem;            // 64 KB: [buf*2+kh]*16384
    char* sB = smem + 65536;    // 64 KB

    const int tid  = threadIdx.x;
    const int lane = tid & 63;
    const int w    = tid >> 6;   // 0..7
    const int wm   = w & 1;      // 128-row half
    const int wn   = w >> 1;     // 0..3: 64-col group
    const int quad = lane >> 4;
    const int l16  = lane & 15;
    const int swz  = (l16 >> 1) & 3;

    // XCD swizzle within batch (256 blocks, 256%8==0 -> bijective)
    const int bx   = blockIdx.x;
    const int z    = blockIdx.y;
    const int wgid = (bx & 7) * 32 + (bx >> 3);
    const int row0 = (wgid >> 4) * 256;
    const int col0 = (wgid & 15) * 256;

    const _Float16* Abase = Q    + (size_t)z * SEQ * HIDDEN + (size_t)row0 * HIDDEN;
    const _Float16* Bbase = Kmat + (size_t)z * SEQ * HIDDEN + (size_t)col0 * HIDDEN;
    E    += (size_t)z * SEQ * SEQ;
    Lsum += (size_t)z * SEQ;

    // per-thread staging chunks: a K-half = 256 rows x 4 chunks = 1024 chunks,
    // 2 wave-issues of 512 contiguous chunks (gld16 dest = uniform + lane*16)
    const int n0 = tid, n1 = tid + 512;
    const int r0s = n0 >> 2, p0s = n0 & 3;
    const int r1s = n1 >> 2, p1s = n1 & 3;
    const int off0 = r0s * HIDDEN + (p0s ^ ((r0s >> 1) & 3)) * 8;  // pre-swizzled src
    const int off1 = r1s * HIDDEN + (p1s ^ ((r1s >> 1) & 3)) * 8;

    auto stage = [&](const _Float16* base, char* lh, int kt, int kh) {
        const int kb = kt * 64 + kh * 32;
        gld16(base + off0 + kb, lh + n0 * 16);
        gld16(base + off1 + kb, lh + n1 * 16);
    };

    floatx4 acc[8][4];
    #pragma unroll
    for (int i = 0; i < 8; ++i)
        #pragma unroll
        for (int j = 0; j < 4; ++j) acc[i][j] = (floatx4){0.f, 0.f, 0.f, 0.f};

    f16x8 afA[4], afB[4], bfX[4], bfY[4];

#define RD_AF(DST, RH, KH, B_)                                                \
  { const f16x8* pAh = (const f16x8*)(sA + ((B_) * 2 + (KH)) * 16384);        \
    _Pragma("unroll")                                                         \
    for (int i = 0; i < 4; ++i)                                               \
      DST[i] = pAh[(wm * 128 + (RH) * 64 + i * 16 + l16) * 4 + (quad ^ swz)]; }

#define RD_BF(DST, KH, B_)                                                    \
  { const f16x8* pBh = (const f16x8*)(sB + ((B_) * 2 + (KH)) * 16384);        \
    _Pragma("unroll")                                                         \
    for (int j = 0; j < 4; ++j)                                               \
      DST[j] = pBh[(wn * 64 + j * 16 + l16) * 4 + (quad ^ swz)]; }

#define MM(RH, AF, BF)                                                        \
  __builtin_amdgcn_sched_barrier(0);                                          \
  __builtin_amdgcn_s_setprio(1);                                              \
  _Pragma("unroll")                                                           \
  for (int j = 0; j < 4; ++j)                                                 \
    _Pragma("unroll")                                                         \
    for (int i = 0; i < 4; ++i)                                               \
      acc[(RH) * 4 + i][j] = __builtin_amdgcn_mfma_f32_16x16x32_f16(          \
          AF[i], BF[j], acc[(RH) * 4 + i][j], 0, 0, 0);                       \
  __builtin_amdgcn_s_setprio(0);

#define QK_TILE(T_, S01, S23, W0S, W2S, RDNEXT)                               \
  { const int b_ = (T_) & 1, nb_ = b_ ^ 1;                                    \
    /* ---- p0 ---- */                                                        \
    __builtin_amdgcn_s_barrier();                                             \
    RD_AF(afB, 1, 0, b_);                                                     \
    if (S01) stage(Abase, sA + (nb_ * 2 + 1) * 16384, (T_) + 1, 1);           \
    MM(0, afA, bfX)                                                           \
    asm volatile("s_waitcnt vmcnt(" W0S ")" ::: "memory");                    \
    /* ---- p1 ---- */                                                        \
    __builtin_amdgcn_s_barrier();                                             \
    RD_AF(afA, 0, 1, b_);                                                     \
    RD_BF(bfY, 1, b_);                                                        \
    if (S01) stage(Bbase, sB + (nb_ * 2 + 1) * 16384, (T_) + 1, 1);           \
    MM(1, afB, bfX)                                                           \
    /* ---- p2 ---- */                                                        \
    __builtin_amdgcn_s_barrier();                                             \
    RD_AF(afB, 1, 1, b_);                                                     \
    if (S23) stage(Abase, sA + (b_ * 2 + 0) * 16384, (T_) + 2, 0);            \
    MM(0, afA, bfY)                                                           \
    if (RDNEXT) asm volatile("s_waitcnt vmcnt(" W2S ")" ::: "memory");        \
    /* ---- p3 ---- */                                                        \
    __builtin_amdgcn_s_barrier();                                             \
    if (RDNEXT) {                                                             \
      RD_AF(afA, 0, 0, nb_);                                                  \
      RD_BF(bfX, 0, nb_);                                                     \
    }                                                                         \
    if (S23) stage(Bbase, sB + (b_ * 2 + 0) * 16384, (T_) + 2, 0);            \
    MM(1, afB, bfY)                                                           \
  }

    // prologue: tile0 (4 halves) + tile1 (kh0 halves); wait BEFORE barrier,
    // then prime p0 frags (vmcnt(8): A0(0),B0(0) landed for every wave)
    stage(Abase, sA + 0 * 16384, 0, 0);   // A0(0)
    stage(Bbase, sB + 0 * 16384, 0, 0);   // B0(0)
    stage(Abase, sA + 1 * 16384, 0, 1);   // A1(0)
    stage(Bbase, sB + 1 * 16384, 0, 1);   // B1(0)
    stage(Abase, sA + 2 * 16384, 1, 0);   // A0(1)
    stage(Bbase, sB + 2 * 16384, 1, 0);   // B0(1)
    asm volatile("s_waitcnt vmcnt(8)" ::: "memory");
    __builtin_amdgcn_s_barrier();
    RD_AF(afA, 0, 0, 0);
    RD_BF(bfX, 0, 0);

    for (int t = 0; t < 14; ++t) QK_TILE(t, 1, 1, "6", "6", 1)
    QK_TILE(14, 1, 0, "6", "4", 1)
    QK_TILE(15, 0, 0, "0", "0", 0)

#undef QK_TILE
#undef MM
#undef RD_BF
#undef RD_AF

    // ---- epilogue: exp2 -> E fp16 + row-sum atomics ----
    #pragma unroll
    for (int i = 0; i < 8; ++i) {
        const int r0 = row0 + wm * 128 + i * 16 + quad * 4;
        float rp[4] = {0.f, 0.f, 0.f, 0.f};
        #pragma unroll
        for (int j = 0; j < 4; ++j) {
            const int cl = col0 + wn * 64 + j * 16 + l16;
            #pragma unroll
            for (int reg = 0; reg < 4; ++reg) {
                const float v = exp2f(alpha * acc[i][j][reg] - 5.770780163555856f);
                const _Float16 vh = (_Float16)v;
                E[(size_t)(r0 + reg) * SEQ + cl] = vh;
                rp[reg] += (float)vh;
            }
        }
        #pragma unroll
        for (int off = 1; off < 16; off <<= 1)
            #pragma unroll
            for (int reg = 0; reg < 4; ++reg)
                rp[reg] += __shfl_xor(rp[reg], off, 64);
        if (l16 == 0)
            #pragma unroll
            for (int reg = 0; reg < 4; ++reg)
                atomicAdd(&Lsum[r0 + reg], rp[reg]);
    }
}

// ===========================================================================
// PV kernel: 128x256 tile, 256 thr = 4 waves (2x2), wave tile 64x128.
// ~180 regs -> 2 blocks/CU (barrier-drain overlap). grid = 512 linear blocks.
// XCD swizzle: the 4 col-tile blocks sharing one E row-strip land on ONE XCD
// with adjacent slots -> shared A-tile K-loop front is an L2 hit (E re-reads
// stop going to HBM). A=E[b] (lda 4096), B=Vt[b] (ldb 4096).
// Cf[r*1024+c] = acc / Lsum[row].
// ===========================================================================
__global__ __launch_bounds__(256, 2)
void gemm_pv_kernel(const _Float16* __restrict__ A,
                    const _Float16* __restrict__ B,
                    float* __restrict__ Cf,
                    const float* __restrict__ Lsum) {
    __shared__ __align__(16) char smem[24576];
    char* sA = smem;            //  8 KB: 128 rows x 32 f16
    char* sB = smem + 8192;     // 16 KB: 256 rows x 32 f16

    const int tid  = threadIdx.x;
    const int lane = tid & 63;
    const int w    = tid >> 6;
    const int wm   = w & 1;           // 64-row half
    const int wn   = w >> 1;          // 128-col half
    const int quad = lane >> 4;
    const int l16  = lane & 15;
    const int swz  = (l16 >> 1) & 3;

    // swizzled decomposition: n%8 = XCD; c fastest within XCD slot group
    const int n    = blockIdx.x;          // 0..511
    const int xcd  = n & 7;
    const int slot = n >> 3;              // 0..63
    const int c    = slot & 3;            // col tile 0..3
    const int rg   = xcd + 8 * (slot >> 2);  // 0..127
    const int r    = rg & 31;             // row tile within batch
    const int bz   = rg >> 5;             // batch

    const int row0 = r * 128;
    const int col0 = c * 256;

    A    += (size_t)bz * SEQ * SEQ;
    B    += (size_t)bz * HIDDEN * SEQ;
    Cf   += (size_t)bz * SEQ * HIDDEN;
    Lsum += (size_t)bz * SEQ;

    floatx4 acc[4][8];
    #pragma unroll
    for (int i = 0; i < 4; ++i)
        #pragma unroll
        for (int j = 0; j < 8; ++j) acc[i][j] = (floatx4){0.f, 0.f, 0.f, 0.f};

    const f16x8* pA = (const f16x8*)sA;
    const f16x8* pB = (const f16x8*)sB;

    for (int k0 = 0; k0 < SEQ; k0 += 32) {
        // A: 512 chunks (2/thread); B: 1024 chunks (4/thread)
        #pragma unroll
        for (int it = 0; it < 2; ++it) {
            const int nc = tid + it * 256;
            const int sr = nc >> 2;
            const int sc = (nc & 3) ^ ((sr >> 1) & 3);
            gld16(A + (size_t)(row0 + sr) * SEQ + k0 + sc * 8, sA + nc * 16);
        }
        #pragma unroll
        for (int it = 0; it < 4; ++it) {
            const int nc = tid + it * 256;
            const int sr = nc >> 2;
            const int sc = (nc & 3) ^ ((sr >> 1) & 3);
            gld16(B + (size_t)(col0 + sr) * SEQ + k0 + sc * 8, sB + nc * 16);
        }
        __syncthreads();

        f16x8 af[4];
        #pragma unroll
        for (int i = 0; i < 4; ++i) {
            const int rr = wm * 64 + i * 16 + l16;
            af[i] = pA[rr * 4 + (quad ^ swz)];
        }
        #pragma unroll
        for (int j = 0; j < 8; ++j) {
            const int cc = wn * 128 + j * 16 + l16;
            const f16x8 bf = pB[cc * 4 + (quad ^ swz)];
            #pragma unroll
            for (int i = 0; i < 4; ++i)
                acc[i][j] = __builtin_amdgcn_mfma_f32_16x16x32_f16(af[i], bf, acc[i][j], 0, 0, 0);
        }
        __syncthreads();
    }

    #pragma unroll
    for (int i = 0; i < 4; ++i) {
        const int r0 = row0 + wm * 64 + i * 16 + quad * 4;
        float linv[4];
        #pragma unroll
        for (int reg = 0; reg < 4; ++reg) linv[reg] = 1.0f / Lsum[r0 + reg];
        #pragma unroll
        for (int j = 0; j < 8; ++j) {
            const int cl = col0 + wn * 128 + j * 16 + l16;
            #pragma unroll
            for (int reg = 0; reg < 4; ++reg)
                Cf[(size_t)(r0 + reg) * HIDDEN + cl] = acc[i][j][reg] * linv[reg];
        }
    }
}

// ---------------------------------------------------------------------------
// fp32 -> fp16 casts
// ---------------------------------------------------------------------------
__global__ __launch_bounds__(256)
void cast_x_kernel(const float* __restrict__ in, _Float16* __restrict__ out) {
    const int i = blockIdx.x * 256 + threadIdx.x;
    const float4 x = ((const float4*)in)[i];
    _Float16 h[4] = {(_Float16)x.x, (_Float16)x.y, (_Float16)x.z, (_Float16)x.w};
    ((uint2*)out)[i] = *(const uint2*)h;
}

__global__ __launch_bounds__(256)
void cast_w_kernel(const float* __restrict__ w0, const float* __restrict__ w1,
                   const float* __restrict__ w2,
                   _Float16* __restrict__ o0, _Float16* __restrict__ o1,
                   _Float16* __restrict__ o2) {
    const float* in = (blockIdx.z == 0) ? w0 : (blockIdx.z == 1) ? w1 : w2;
    _Float16* out   = (blockIdx.z == 0) ? o0 : (blockIdx.z == 1) ? o1 : o2;
    const int i = blockIdx.x * 256 + threadIdx.x;
    const float4 x = ((const float4*)in)[i];
    _Float16 h[4] = {(_Float16)x.x, (_Float16)x.y, (_Float16)x.z, (_Float16)x.w};
    ((uint2*)out)[i] = *(const uint2*)h;
}

// ---------------------------------------------------------------------------
// ws layout (bytes), total ~235 MB:
//   [0, 134.2M) : E fp16 [B][S][S]  (head aliases Xh + W casts, dead by then)
//   then        : Qh 33.5M | Kh 33.5M | Vt [B][H][S] 33.5M | Lsum 64K
// ---------------------------------------------------------------------------
extern "C" void kernel_launch(void* const* d_in, const int* in_sizes, int n_in,
                              void* d_out, int out_size, void* d_ws, size_t ws_size,
                              hipStream_t stream) {
    const float* X  = (const float*)d_in[0];
    const float* Wq = (const float*)d_in[1];
    const float* bq = (const float*)d_in[2];
    const float* Wk = (const float*)d_in[3];
    const float* bk = (const float*)d_in[4];
    const float* Wv = (const float*)d_in[5];
    const float* bv = (const float*)d_in[6];
    float* out = (float*)d_out;

    char* ws = (char*)d_ws;
    const size_t EB = (size_t)BATCH * SEQ * SEQ * 2;     // 134,217,728
    const size_t XB = (size_t)BATCH * SEQ * HIDDEN * 2;  // 33,554,432
    const size_t WB = (size_t)HIDDEN * HIDDEN * 2;       // 2,097,152

    _Float16* E   = (_Float16*)ws;
    _Float16* Xh  = (_Float16*)ws;                       // aliases E head
    _Float16* Wqh = (_Float16*)(ws + XB);
    _Float16* Wkh = (_Float16*)(ws + XB + WB);
    _Float16* Wvh = (_Float16*)(ws + XB + 2 * WB);
    _Float16* Qh  = (_Float16*)(ws + EB);
    _Float16* Kh  = (_Float16*)(ws + EB + XB);
    _Float16* Vt  = (_Float16*)(ws + EB + 2 * XB);       // [B][H][S]
    float*    Lsum= (float*)   (ws + EB + 3 * XB);       // [B][S]

    // 1. casts
    cast_x_kernel<<<dim3(16384), dim3(256), 0, stream>>>(X, Xh);
    cast_w_kernel<<<dim3(1024, 1, 3), dim3(256), 0, stream>>>(
        Wq, Wk, Wv, Wqh, Wkh, Wvh);

    hipMemsetAsync(Lsum, 0, (size_t)BATCH * SEQ * sizeof(float), stream);

    // 2. fused QKV projection: [16384,1024] x [3072,1024]^T, 128^2 tiles
    gemm128_kernel<5><<<dim3(24, 128, 1), dim3(256), 0, stream>>>(
        Xh, Wqh, Wkh, Wvh, bq, bk, bv, 1.0f,
        nullptr, Qh, Kh, Vt, nullptr,
        HIDDEN, HIDDEN, HIDDEN);

    // 3. QK^T -> exp -> E (fp16) + row sums: 256^2 tiles, frag-dbuf pipeline
    const float alpha2 = (1.0f / 32.0f) * 1.4426950408889634f;  // /sqrt(H)*log2e
    qk8_kernel<<<dim3(256, 4), dim3(512), 0, stream>>>(Qh, Kh, E, Lsum, alpha2);

    // 4. PV with 1/Lsum scaling, 128x256 tiles + XCD swizzle
    gemm_pv_kernel<<<dim3(512), dim3(256), 0, stream>>>(E, Vt, out, Lsum);
}

// Round 4
// 527.014 us; speedup vs baseline: 1.1330x; 1.1330x over previous
//
#include <hip/hip_runtime.h>
#include <math.h>

#define HIDDEN 1024
#define SEQ    4096
#define BATCH  4

typedef _Float16 f16x8 __attribute__((ext_vector_type(8)));
typedef float    floatx4 __attribute__((ext_vector_type(4)));

// async 16B global->LDS copy (m97: width=16 emits global_load_lds_dwordx4)
__device__ inline void gld16(const void* g, void* l) {
    __builtin_amdgcn_global_load_lds(
        (const __attribute__((address_space(1))) unsigned int*)g,
        (__attribute__((address_space(3))) unsigned int*)l, 16, 0, 0);
}

// ===========================================================================
// Unified 256x256-tile GEMM, BK=64, 512 thr = 8 waves (2M x 4N), wave tile
// 128x64. LDS 128 KB = {A,B} x {2 dbuf} x {2 K-halves} x [256][32]f16.
//
// Fragment double-buffer with read-ahead-1 (proven R3): phase p issues the
// ds_reads for phase p+1 (alternate frag regs), then MFMAs the current frags
// -> LDS service overlaps matrix-pipe backpressure. B-fragments (kh-only)
// read once per tile. Counted vmcnt waits go BEFORE the barrier that gates
// the dependent reads (vmcnt is PER-WAVE; staging is cooperative across all
// 8 waves -- wait -> barrier -> read is the only safe order).
//
// Phase map (tile T, b=T&1, nb=b^1):
//  p0: rd afB<-(RH1,kh0,b)  stage A-kh1(T+1)->nb  MFMA(RH0,afA,bfX)  vm(6)
//  p1: rd afA<-(RH0,kh1,b), bfY<-(kh1,b)
//                           stage B-kh1(T+1)->nb  MFMA(RH1,afB,bfX)
//  p2: rd afB<-(RH1,kh1,b)  stage A-kh0(T+2)->b   MFMA(RH0,afA,bfY)  vm(6)
//  p3: rd afA<-(RH0,kh0,nb), bfX<-(kh0,nb)
//                           stage B-kh0(T+2)->b   MFMA(RH1,afB,bfY)
// Tail waits: tile NT-2 = 6/4, tile NT-1 = 0/none.
//
// MODE 5: fused QKV projection. A=Xh [16384,1024], B=W{q,k,v} [1024,1024].
//         grid 768 linear = 64 row-tiles x 12 col-tiles, XCD-swizzled.
//         which = col0>>10 picks Wq/Wk/Wv; which<2 -> Qo/Ko[r*1024+cl];
//         which==2 -> Vt[(b*1024+cl)*4096+s] (transposed store).
// MODE 3: QK^T -> exp2 -> E fp16 + Lsum atomics. grid (256,4), NT=16.
// MODE 4: PV. A=E[b] (lda 4096), B=Vt[b] (ldb 4096), NT=64.
//         out = acc / Lsum[row]. grid (64,4) = 16 row x 4 col, XCD-swizzled.
// ===========================================================================
template<int MODE, int NT>
__global__ __launch_bounds__(512)
void gemm256_kernel(const _Float16* __restrict__ A,
                    const _Float16* __restrict__ Bq,
                    const _Float16* __restrict__ Bk,
                    const _Float16* __restrict__ Bv,
                    const float* __restrict__ bq,
                    const float* __restrict__ bk,
                    const float* __restrict__ bv,
                    float alpha,
                    _Float16* __restrict__ Eo,
                    _Float16* __restrict__ Qo,
                    _Float16* __restrict__ Ko,
                    _Float16* __restrict__ Vo,
                    float* __restrict__ Cf,
                    float* __restrict__ Lsum) {
    constexpr int LDAB = (MODE == 4) ? SEQ : HIDDEN;   // row stride, both ops
    __shared__ __align__(16) char smem[131072];
    char* sA = smem;            // 64 KB: [buf*2+kh]*16384
    char* sB = smem + 65536;    // 64 KB

    const int tid  = threadIdx.x;
    const int lane = tid & 63;
    const int w    = tid >> 6;   // 0..7
    const int wm   = w & 1;      // 128-row half
    const int wn   = w >> 1;     // 0..3: 64-col group
    const int quad = lane >> 4;
    const int l16  = lane & 15;
    const int swz  = (l16 >> 1) & 3;

    int row0, col0, z = 0;
    if constexpr (MODE == 5) {
        // 768 blocks: xcd = n&7, 96 slots, 12 col-tiles fastest within XCD
        const int n = blockIdx.x, xcd = n & 7, slot = n >> 3;
        const int cc = slot % 12, rg = xcd + 8 * (slot / 12);  // rg 0..63
        row0 = rg * 256; col0 = cc * 256;
    } else if constexpr (MODE == 3) {
        z = blockIdx.y;
        const int bx = blockIdx.x, wgid = (bx & 7) * 32 + (bx >> 3);
        row0 = (wgid >> 4) * 256; col0 = (wgid & 15) * 256;
    } else {  // MODE 4
        z = blockIdx.y;
        const int n = blockIdx.x, xcd = n & 7, slot = n >> 3;  // slot 0..7
        const int cc = slot & 3, rg = xcd + 8 * (slot >> 2);   // rg 0..15
        row0 = rg * 256; col0 = cc * 256;
    }

    const _Float16* Abase;
    const _Float16* Bbase;
    int colbase = col0, which = 0;
    if constexpr (MODE == 5) {
        which = col0 >> 10; colbase = col0 & 1023;
        const _Float16* Bsrc = (which == 0) ? Bq : (which == 1) ? Bk : Bv;
        Abase = A + (size_t)row0 * HIDDEN;
        Bbase = Bsrc + (size_t)colbase * HIDDEN;
    } else if constexpr (MODE == 3) {
        Abase = A  + (size_t)z * SEQ * HIDDEN + (size_t)row0 * HIDDEN;
        Bbase = Bq + (size_t)z * SEQ * HIDDEN + (size_t)col0 * HIDDEN;
        Eo   += (size_t)z * SEQ * SEQ;
        Lsum += (size_t)z * SEQ;
    } else {
        Abase = A  + (size_t)z * SEQ * SEQ    + (size_t)row0 * SEQ;
        Bbase = Bq + (size_t)z * HIDDEN * SEQ + (size_t)col0 * SEQ;
        Cf   += (size_t)z * SEQ * HIDDEN;
        Lsum += (size_t)z * SEQ;
    }

    // per-thread staging chunks: a K-half = 256 rows x 4 chunks = 1024 chunks,
    // 2 wave-issues of 512 contiguous chunks (gld16 dest = uniform + lane*16)
    const int n0 = tid, n1 = tid + 512;
    const int r0s = n0 >> 2, p0s = n0 & 3;
    const int r1s = n1 >> 2, p1s = n1 & 3;
    const int off0 = r0s * LDAB + (p0s ^ ((r0s >> 1) & 3)) * 8;  // pre-swizzled src
    const int off1 = r1s * LDAB + (p1s ^ ((r1s >> 1) & 3)) * 8;

    auto stage = [&](const _Float16* base, char* lh, int kt, int kh) {
        const int kb = kt * 64 + kh * 32;
        gld16(base + off0 + kb, lh + n0 * 16);
        gld16(base + off1 + kb, lh + n1 * 16);
    };

    floatx4 acc[8][4];
    #pragma unroll
    for (int i = 0; i < 8; ++i)
        #pragma unroll
        for (int j = 0; j < 4; ++j) acc[i][j] = (floatx4){0.f, 0.f, 0.f, 0.f};

    f16x8 afA[4], afB[4], bfX[4], bfY[4];

#define RD_AF(DST, RH, KH, B_)                                                \
  { const f16x8* pAh = (const f16x8*)(sA + ((B_) * 2 + (KH)) * 16384);        \
    _Pragma("unroll")                                                         \
    for (int i = 0; i < 4; ++i)                                               \
      DST[i] = pAh[(wm * 128 + (RH) * 64 + i * 16 + l16) * 4 + (quad ^ swz)]; }

#define RD_BF(DST, KH, B_)                                                    \
  { const f16x8* pBh = (const f16x8*)(sB + ((B_) * 2 + (KH)) * 16384);        \
    _Pragma("unroll")                                                         \
    for (int j = 0; j < 4; ++j)                                               \
      DST[j] = pBh[(wn * 64 + j * 16 + l16) * 4 + (quad ^ swz)]; }

#define MM(RH, AF, BF)                                                        \
  __builtin_amdgcn_sched_barrier(0);                                          \
  __builtin_amdgcn_s_setprio(1);                                              \
  _Pragma("unroll")                                                           \
  for (int j = 0; j < 4; ++j)                                                 \
    _Pragma("unroll")                                                         \
    for (int i = 0; i < 4; ++i)                                               \
      acc[(RH) * 4 + i][j] = __builtin_amdgcn_mfma_f32_16x16x32_f16(          \
          AF[i], BF[j], acc[(RH) * 4 + i][j], 0, 0, 0);                       \
  __builtin_amdgcn_s_setprio(0);

#define QK_TILE(T_, S01, S23, W0S, W2S, RDNEXT)                               \
  { const int b_ = (T_) & 1, nb_ = b_ ^ 1;                                    \
    /* ---- p0 ---- */                                                        \
    __builtin_amdgcn_s_barrier();                                             \
    RD_AF(afB, 1, 0, b_);                                                     \
    if (S01) stage(Abase, sA + (nb_ * 2 + 1) * 16384, (T_) + 1, 1);           \
    MM(0, afA, bfX)                                                           \
    asm volatile("s_waitcnt vmcnt(" W0S ")" ::: "memory");                    \
    /* ---- p1 ---- */                                                        \
    __builtin_amdgcn_s_barrier();                                             \
    RD_AF(afA, 0, 1, b_);                                                     \
    RD_BF(bfY, 1, b_);                                                        \
    if (S01) stage(Bbase, sB + (nb_ * 2 + 1) * 16384, (T_) + 1, 1);           \
    MM(1, afB, bfX)                                                           \
    /* ---- p2 ---- */                                                        \
    __builtin_amdgcn_s_barrier();                                             \
    RD_AF(afB, 1, 1, b_);                                                     \
    if (S23) stage(Abase, sA + (b_ * 2 + 0) * 16384, (T_) + 2, 0);            \
    MM(0, afA, bfY)                                                           \
    if (RDNEXT) asm volatile("s_waitcnt vmcnt(" W2S ")" ::: "memory");        \
    /* ---- p3 ---- */                                                        \
    __builtin_amdgcn_s_barrier();                                             \
    if (RDNEXT) {                                                             \
      RD_AF(afA, 0, 0, nb_);                                                  \
      RD_BF(bfX, 0, nb_);                                                     \
    }                                                                         \
    if (S23) stage(Bbase, sB + (b_ * 2 + 0) * 16384, (T_) + 2, 0);            \
    MM(1, afB, bfY)                                                           \
  }

    // prologue: tile0 (4 halves) + tile1 (kh0 halves); wait BEFORE barrier,
    // then prime p0 frags (vmcnt(8): A0(0),B0(0) landed for every wave)
    stage(Abase, sA + 0 * 16384, 0, 0);   // A0(0)
    stage(Bbase, sB + 0 * 16384, 0, 0);   // B0(0)
    stage(Abase, sA + 1 * 16384, 0, 1);   // A1(0)
    stage(Bbase, sB + 1 * 16384, 0, 1);   // B1(0)
    stage(Abase, sA + 2 * 16384, 1, 0);   // A0(1)
    stage(Bbase, sB + 2 * 16384, 1, 0);   // B0(1)
    asm volatile("s_waitcnt vmcnt(8)" ::: "memory");
    __builtin_amdgcn_s_barrier();
    RD_AF(afA, 0, 0, 0);
    RD_BF(bfX, 0, 0);

    #pragma unroll 2
    for (int t = 0; t < NT - 2; ++t) QK_TILE(t, 1, 1, "6", "6", 1)
    QK_TILE(NT - 2, 1, 0, "6", "4", 1)
    QK_TILE(NT - 1, 0, 0, "0", "0", 0)

#undef QK_TILE
#undef MM
#undef RD_BF
#undef RD_AF

    // ---- epilogue (C/D layout: col=lane&15, row=quad*4+reg) ----
    #pragma unroll
    for (int i = 0; i < 8; ++i) {
        const int r0 = row0 + wm * 128 + i * 16 + quad * 4;
        if constexpr (MODE == 3) {
            float rp[4] = {0.f, 0.f, 0.f, 0.f};
            #pragma unroll
            for (int j = 0; j < 4; ++j) {
                const int cl = col0 + wn * 64 + j * 16 + l16;
                #pragma unroll
                for (int reg = 0; reg < 4; ++reg) {
                    const float v = exp2f(alpha * acc[i][j][reg] - 5.770780163555856f);
                    const _Float16 vh = (_Float16)v;
                    Eo[(size_t)(r0 + reg) * SEQ + cl] = vh;
                    rp[reg] += (float)vh;
                }
            }
            #pragma unroll
            for (int off = 1; off < 16; off <<= 1)
                #pragma unroll
                for (int reg = 0; reg < 4; ++reg)
                    rp[reg] += __shfl_xor(rp[reg], off, 64);
            if (l16 == 0)
                #pragma unroll
                for (int reg = 0; reg < 4; ++reg)
                    atomicAdd(&Lsum[r0 + reg], rp[reg]);
        } else if constexpr (MODE == 5) {
            #pragma unroll
            for (int j = 0; j < 4; ++j) {
                const int cl = colbase + wn * 64 + j * 16 + l16;
                const float bcol = (which == 0 ? bq : which == 1 ? bk : bv)[cl];
                if (which < 2) {
                    _Float16* O = (which == 0) ? Qo : Ko;
                    #pragma unroll
                    for (int reg = 0; reg < 4; ++reg)
                        O[(size_t)(r0 + reg) * HIDDEN + cl] =
                            (_Float16)(acc[i][j][reg] + bcol);
                } else {
                    const int bb = r0 >> 12;
                    const int s  = r0 & 4095;
                    _Float16 tq[4];
                    #pragma unroll
                    for (int reg = 0; reg < 4; ++reg)
                        tq[reg] = (_Float16)(acc[i][j][reg] + bcol);
                    *(uint2*)&Vo[((size_t)bb * HIDDEN + cl) * SEQ + s] = *(const uint2*)tq;
                }
            }
        } else {  // MODE 4: PV, scale by 1/Lsum
            float linv[4];
            #pragma unroll
            for (int reg = 0; reg < 4; ++reg) linv[reg] = 1.0f / Lsum[r0 + reg];
            #pragma unroll
            for (int j = 0; j < 4; ++j) {
                const int cl = col0 + wn * 64 + j * 16 + l16;
                #pragma unroll
                for (int reg = 0; reg < 4; ++reg)
                    Cf[(size_t)(r0 + reg) * HIDDEN + cl] = acc[i][j][reg] * linv[reg];
            }
        }
    }
}

// ---------------------------------------------------------------------------
// fp32 -> fp16 casts
// ---------------------------------------------------------------------------
__global__ __launch_bounds__(256)
void cast_x_kernel(const float* __restrict__ in, _Float16* __restrict__ out) {
    const int i = blockIdx.x * 256 + threadIdx.x;
    const float4 x = ((const float4*)in)[i];
    _Float16 h[4] = {(_Float16)x.x, (_Float16)x.y, (_Float16)x.z, (_Float16)x.w};
    ((uint2*)out)[i] = *(const uint2*)h;
}

__global__ __launch_bounds__(256)
void cast_w_kernel(const float* __restrict__ w0, const float* __restrict__ w1,
                   const float* __restrict__ w2,
                   _Float16* __restrict__ o0, _Float16* __restrict__ o1,
                   _Float16* __restrict__ o2) {
    const float* in = (blockIdx.z == 0) ? w0 : (blockIdx.z == 1) ? w1 : w2;
    _Float16* out   = (blockIdx.z == 0) ? o0 : (blockIdx.z == 1) ? o1 : o2;
    const int i = blockIdx.x * 256 + threadIdx.x;
    const float4 x = ((const float4*)in)[i];
    _Float16 h[4] = {(_Float16)x.x, (_Float16)x.y, (_Float16)x.z, (_Float16)x.w};
    ((uint2*)out)[i] = *(const uint2*)h;
}

// ---------------------------------------------------------------------------
// ws layout (bytes), total ~235 MB:
//   [0, 134.2M) : E fp16 [B][S][S]  (head aliases Xh + W casts, dead by then)
//   then        : Qh 33.5M | Kh 33.5M | Vt [B][H][S] 33.5M | Lsum 64K
// ---------------------------------------------------------------------------
extern "C" void kernel_launch(void* const* d_in, const int* in_sizes, int n_in,
                              void* d_out, int out_size, void* d_ws, size_t ws_size,
                              hipStream_t stream) {
    const float* X  = (const float*)d_in[0];
    const float* Wq = (const float*)d_in[1];
    const float* bq = (const float*)d_in[2];
    const float* Wk = (const float*)d_in[3];
    const float* bk = (const float*)d_in[4];
    const float* Wv = (const float*)d_in[5];
    const float* bv = (const float*)d_in[6];
    float* out = (float*)d_out;

    char* ws = (char*)d_ws;
    const size_t EB = (size_t)BATCH * SEQ * SEQ * 2;     // 134,217,728
    const size_t XB = (size_t)BATCH * SEQ * HIDDEN * 2;  // 33,554,432
    const size_t WB = (size_t)HIDDEN * HIDDEN * 2;       // 2,097,152

    _Float16* E   = (_Float16*)ws;
    _Float16* Xh  = (_Float16*)ws;                       // aliases E head
    _Float16* Wqh = (_Float16*)(ws + XB);
    _Float16* Wkh = (_Float16*)(ws + XB + WB);
    _Float16* Wvh = (_Float16*)(ws + XB + 2 * WB);
    _Float16* Qh  = (_Float16*)(ws + EB);
    _Float16* Kh  = (_Float16*)(ws + EB + XB);
    _Float16* Vt  = (_Float16*)(ws + EB + 2 * XB);       // [B][H][S]
    float*    Lsum= (float*)   (ws + EB + 3 * XB);       // [B][S]

    // 1. casts
    cast_x_kernel<<<dim3(16384), dim3(256), 0, stream>>>(X, Xh);
    cast_w_kernel<<<dim3(1024, 1, 3), dim3(256), 0, stream>>>(
        Wq, Wk, Wv, Wqh, Wkh, Wvh);

    hipMemsetAsync(Lsum, 0, (size_t)BATCH * SEQ * sizeof(float), stream);

    // 2. fused QKV projection: [16384,1024] x [3072,1024]^T, 256^2 tiles
    gemm256_kernel<5, 16><<<dim3(768), dim3(512), 0, stream>>>(
        Xh, Wqh, Wkh, Wvh, bq, bk, bv, 0.f,
        nullptr, Qh, Kh, Vt, nullptr, nullptr);

    // 3. QK^T -> exp -> E (fp16) + row sums: 256^2 tiles, frag-dbuf pipeline
    const float alpha2 = (1.0f / 32.0f) * 1.4426950408889634f;  // /sqrt(H)*log2e
    gemm256_kernel<3, 16><<<dim3(256, 4), dim3(512), 0, stream>>>(
        Qh, Kh, nullptr, nullptr, nullptr, nullptr, nullptr, alpha2,
        E, nullptr, nullptr, nullptr, nullptr, Lsum);

    // 4. PV with 1/Lsum scaling: 256^2 tiles, NT=64
    gemm256_kernel<4, 64><<<dim3(64, 4), dim3(512), 0, stream>>>(
        E, Vt, nullptr, nullptr, nullptr, nullptr, nullptr, 0.f,
        nullptr, nullptr, nullptr, nullptr, out, Lsum);
}

// Round 6
// 518.897 us; speedup vs baseline: 1.1507x; 1.0156x over previous
//
#include <hip/hip_runtime.h>
#include <math.h>

#define HIDDEN 1024
#define SEQ    4096
#define BATCH  4

typedef _Float16 f16x8 __attribute__((ext_vector_type(8)));
typedef float    floatx4 __attribute__((ext_vector_type(4)));

// async 16B global->LDS copy (m97: width=16 emits global_load_lds_dwordx4)
__device__ inline void gld16(const void* g, void* l) {
    __builtin_amdgcn_global_load_lds(
        (const __attribute__((address_space(1))) unsigned int*)g,
        (__attribute__((address_space(3))) unsigned int*)l, 16, 0, 0);
}

// ===========================================================================
// Unified 256x256-tile GEMM, BK=32, 512 thr = 8 waves (2M x 4N), wave tile
// 128x64. LDS 64 KB = {A,B} x {2 dbuf} x [256][32]f16  ->  2 blocks/CU for
// MODE 3/5 (16 waves, 4/SIMD): co-resident block's MFMA covers barrier skew,
// lgkm latency, staging waits, prologue and the heavy MODE-3 epilogue.
//
// Per K-tile t (buf b=t&1, nb=b^1), ONE barrier + ONE self-drain vmcnt:
//   [vmcnt(0); s_barrier]            // t's buffers landed (staged last tile;
//                                    // queue holds ONLY those 4 loads ->
//                                    // drain-0 == counted wait, no future
//                                    // loads lost; wait BEFORE barrier: vmcnt
//                                    // is per-wave, staging is cooperative)
//   rd afA(RH0,b) 4, bfX(b) 4, afB(RH1,b) 4    // 12 ds_read_b128
//   stage A(t+1)->nb                 // 2 gld16
//   MFMA x16 (RH0: afA x bfX)        // compiler waits lgkmcnt(4): afB flies
//   stage B(t+1)->nb                 // 2 gld16
//   MFMA x16 (RH1: afB x bfX)        // afB serviced under RH0's 620 cy
// LDS write/read disjoint by construction (writes->nb, reads->b); all reads
// of b are lgkm-drained before their wave reaches the next barrier.
//
// MODE 5: fused QKV projection. A=Xh [16384,1024], B=W{q,k,v} [1024,1024].
//         grid 768 = 64 row x 12 col tiles, XCD-swizzled. which = col0>>10;
//         which<2 -> Qo/Ko[r*1024+cl]; which==2 -> Vt[(b*1024+cl)*4096+s].
// MODE 3: QK^T -> exp2 -> E fp16 + Lsum atomics. grid (256,4), NT=32.
// MODE 4: PV. A=E[b] (lda 4096), B=Vt[b] (ldb 4096), NT=128, grid (64,4).
//         out = acc / Lsum[row].
// ===========================================================================
template<int MODE, int NT>
__global__ __launch_bounds__(512)
void gemm256_kernel(const _Float16* __restrict__ A,
                    const _Float16* __restrict__ Bq,
                    const _Float16* __restrict__ Bk,
                    const _Float16* __restrict__ Bv,
                    const float* __restrict__ bq,
                    const float* __restrict__ bk,
                    const float* __restrict__ bv,
                    float alpha,
                    _Float16* __restrict__ Eo,
                    _Float16* __restrict__ Qo,
                    _Float16* __restrict__ Ko,
                    _Float16* __restrict__ Vo,
                    float* __restrict__ Cf,
                    float* __restrict__ Lsum) {
    constexpr int LDAB = (MODE == 4) ? SEQ : HIDDEN;   // row stride, both ops
    __shared__ __align__(16) char smem[65536];
    char* sA = smem;            // 32 KB: [buf]*16384
    char* sB = smem + 32768;    // 32 KB

    const int tid  = threadIdx.x;
    const int lane = tid & 63;
    const int w    = tid >> 6;   // 0..7
    const int wm   = w & 1;      // 128-row half
    const int wn   = w >> 1;     // 0..3: 64-col group
    const int quad = lane >> 4;
    const int l16  = lane & 15;
    const int swz  = (l16 >> 1) & 3;

    int row0, col0, z = 0;
    if constexpr (MODE == 5) {
        // 768 blocks: xcd = n&7, 96 slots, 12 col-tiles fastest within XCD
        const int n = blockIdx.x, xcd = n & 7, slot = n >> 3;
        const int cc = slot % 12, rg = xcd + 8 * (slot / 12);  // rg 0..63
        row0 = rg * 256; col0 = cc * 256;
    } else if constexpr (MODE == 3) {
        z = blockIdx.y;
        const int bx = blockIdx.x, wgid = (bx & 7) * 32 + (bx >> 3);
        row0 = (wgid >> 4) * 256; col0 = (wgid & 15) * 256;
    } else {  // MODE 4
        z = blockIdx.y;
        const int n = blockIdx.x, xcd = n & 7, slot = n >> 3;  // slot 0..7
        const int cc = slot & 3, rg = xcd + 8 * (slot >> 2);   // rg 0..15
        row0 = rg * 256; col0 = cc * 256;
    }

    const _Float16* Abase;
    const _Float16* Bbase;
    int colbase = col0, which = 0;
    if constexpr (MODE == 5) {
        which = col0 >> 10; colbase = col0 & 1023;
        const _Float16* Bsrc = (which == 0) ? Bq : (which == 1) ? Bk : Bv;
        Abase = A + (size_t)row0 * HIDDEN;
        Bbase = Bsrc + (size_t)colbase * HIDDEN;
    } else if constexpr (MODE == 3) {
        Abase = A  + (size_t)z * SEQ * HIDDEN + (size_t)row0 * HIDDEN;
        Bbase = Bq + (size_t)z * SEQ * HIDDEN + (size_t)col0 * HIDDEN;
        Eo   += (size_t)z * SEQ * SEQ;
        Lsum += (size_t)z * SEQ;
    } else {
        Abase = A  + (size_t)z * SEQ * SEQ    + (size_t)row0 * SEQ;
        Bbase = Bq + (size_t)z * HIDDEN * SEQ + (size_t)col0 * SEQ;
        Cf   += (size_t)z * SEQ * HIDDEN;
        Lsum += (size_t)z * SEQ;
    }

    // per-thread staging chunks: a K-tile of A (or B) = 256 rows x 4 chunks
    // = 1024 chunks; 512 thr -> 2 gld16 each (dest = uniform + lane*16)
    const int n0 = tid, n1 = tid + 512;
    const int r0s = n0 >> 2, p0s = n0 & 3;
    const int r1s = n1 >> 2, p1s = n1 & 3;
    const int off0 = r0s * LDAB + (p0s ^ ((r0s >> 1) & 3)) * 8;  // pre-swizzled src
    const int off1 = r1s * LDAB + (p1s ^ ((r1s >> 1) & 3)) * 8;

    auto stage = [&](const _Float16* base, char* lh, int kt) {
        const int kb = kt * 32;
        gld16(base + off0 + kb, lh + n0 * 16);
        gld16(base + off1 + kb, lh + n1 * 16);
    };

    floatx4 acc[8][4];
    #pragma unroll
    for (int i = 0; i < 8; ++i)
        #pragma unroll
        for (int j = 0; j < 4; ++j) acc[i][j] = (floatx4){0.f, 0.f, 0.f, 0.f};

    f16x8 afA[4], afB[4], bfX[4];

#define RD_AF(DST, RH, B_)                                                    \
  { const f16x8* pAh = (const f16x8*)(sA + (B_) * 16384);                     \
    _Pragma("unroll")                                                         \
    for (int i = 0; i < 4; ++i)                                               \
      DST[i] = pAh[(wm * 128 + (RH) * 64 + i * 16 + l16) * 4 + (quad ^ swz)]; }

#define RD_BF(DST, B_)                                                        \
  { const f16x8* pBh = (const f16x8*)(sB + (B_) * 16384);                     \
    _Pragma("unroll")                                                         \
    for (int j = 0; j < 4; ++j)                                               \
      DST[j] = pBh[(wn * 64 + j * 16 + l16) * 4 + (quad ^ swz)]; }

#define MM(RH, AF, BF)                                                        \
  __builtin_amdgcn_sched_barrier(0);                                          \
  __builtin_amdgcn_s_setprio(1);                                              \
  _Pragma("unroll")                                                           \
  for (int j = 0; j < 4; ++j)                                                 \
    _Pragma("unroll")                                                         \
    for (int i = 0; i < 4; ++i)                                               \
      acc[(RH) * 4 + i][j] = __builtin_amdgcn_mfma_f32_16x16x32_f16(          \
          AF[i], BF[j], acc[(RH) * 4 + i][j], 0, 0, 0);                       \
  __builtin_amdgcn_s_setprio(0);

#define QTILE(T_, STG)                                                        \
  { const int b_ = (T_) & 1, nb_ = b_ ^ 1;                                    \
    asm volatile("s_waitcnt vmcnt(0)" ::: "memory");                          \
    __builtin_amdgcn_s_barrier();                                             \
    RD_AF(afA, 0, b_);                                                        \
    RD_BF(bfX, b_);                                                           \
    RD_AF(afB, 1, b_);                                                        \
    if (STG) stage(Abase, sA + nb_ * 16384, (T_) + 1);                        \
    MM(0, afA, bfX)                                                           \
    if (STG) stage(Bbase, sB + nb_ * 16384, (T_) + 1);                        \
    MM(1, afB, bfX)                                                           \
  }

    // prologue: tile 0 -> buf 0
    stage(Abase, sA, 0);
    stage(Bbase, sB, 0);

    #pragma unroll 2
    for (int t = 0; t < NT - 1; ++t) QTILE(t, 1)
    QTILE(NT - 1, 0)

#undef QTILE
#undef MM
#undef RD_BF
#undef RD_AF

    // ---- epilogue (C/D layout: col=lane&15, row=quad*4+reg) ----
    #pragma unroll
    for (int i = 0; i < 8; ++i) {
        const int r0 = row0 + wm * 128 + i * 16 + quad * 4;
        if constexpr (MODE == 3) {
            float rp[4] = {0.f, 0.f, 0.f, 0.f};
            #pragma unroll
            for (int j = 0; j < 4; ++j) {
                const int cl = col0 + wn * 64 + j * 16 + l16;
                #pragma unroll
                for (int reg = 0; reg < 4; ++reg) {
                    const float v = exp2f(alpha * acc[i][j][reg] - 5.770780163555856f);
                    const _Float16 vh = (_Float16)v;
                    Eo[(size_t)(r0 + reg) * SEQ + cl] = vh;
                    rp[reg] += (float)vh;
                }
            }
            #pragma unroll
            for (int off = 1; off < 16; off <<= 1)
                #pragma unroll
                for (int reg = 0; reg < 4; ++reg)
                    rp[reg] += __shfl_xor(rp[reg], off, 64);
            if (l16 == 0)
                #pragma unroll
                for (int reg = 0; reg < 4; ++reg)
                    atomicAdd(&Lsum[r0 + reg], rp[reg]);
        } else if constexpr (MODE == 5) {
            #pragma unroll
            for (int j = 0; j < 4; ++j) {
                const int cl = colbase + wn * 64 + j * 16 + l16;
                const float bcol = (which == 0 ? bq : which == 1 ? bk : bv)[cl];
                if (which < 2) {
                    _Float16* O = (which == 0) ? Qo : Ko;
                    #pragma unroll
                    for (int reg = 0; reg < 4; ++reg)
                        O[(size_t)(r0 + reg) * HIDDEN + cl] =
                            (_Float16)(acc[i][j][reg] + bcol);
                } else {
                    const int bb = r0 >> 12;
                    const int s  = r0 & 4095;
                    _Float16 tq[4];
                    #pragma unroll
                    for (int reg = 0; reg < 4; ++reg)
                        tq[reg] = (_Float16)(acc[i][j][reg] + bcol);
                    *(uint2*)&Vo[((size_t)bb * HIDDEN + cl) * SEQ + s] = *(const uint2*)tq;
                }
            }
        } else {  // MODE 4: PV, scale by 1/Lsum
            float linv[4];
            #pragma unroll
            for (int reg = 0; reg < 4; ++reg) linv[reg] = 1.0f / Lsum[r0 + reg];
            #pragma unroll
            for (int j = 0; j < 4; ++j) {
                const int cl = col0 + wn * 64 + j * 16 + l16;
                #pragma unroll
                for (int reg = 0; reg < 4; ++reg)
                    Cf[(size_t)(r0 + reg) * HIDDEN + cl] = acc[i][j][reg] * linv[reg];
            }
        }
    }
}

// ---------------------------------------------------------------------------
// fp32 -> fp16 casts
// ---------------------------------------------------------------------------
__global__ __launch_bounds__(256)
void cast_x_kernel(const float* __restrict__ in, _Float16* __restrict__ out) {
    const int i = blockIdx.x * 256 + threadIdx.x;
    const float4 x = ((const float4*)in)[i];
    _Float16 h[4] = {(_Float16)x.x, (_Float16)x.y, (_Float16)x.z, (_Float16)x.w};
    ((uint2*)out)[i] = *(const uint2*)h;
}

__global__ __launch_bounds__(256)
void cast_w_kernel(const float* __restrict__ w0, const float* __restrict__ w1,
                   const float* __restrict__ w2,
                   _Float16* __restrict__ o0, _Float16* __restrict__ o1,
                   _Float16* __restrict__ o2) {
    const float* in = (blockIdx.z == 0) ? w0 : (blockIdx.z == 1) ? w1 : w2;
    _Float16* out   = (blockIdx.z == 0) ? o0 : (blockIdx.z == 1) ? o1 : o2;
    const int i = blockIdx.x * 256 + threadIdx.x;
    const float4 x = ((const float4*)in)[i];
    _Float16 h[4] = {(_Float16)x.x, (_Float16)x.y, (_Float16)x.z, (_Float16)x.w};
    ((uint2*)out)[i] = *(const uint2*)h;
}

// ---------------------------------------------------------------------------
// ws layout (bytes), total ~235 MB:
//   [0, 134.2M) : E fp16 [B][S][S]  (head aliases Xh + W casts, dead by then)
//   then        : Qh 33.5M | Kh 33.5M | Vt [B][H][S] 33.5M | Lsum 64K
// ---------------------------------------------------------------------------
extern "C" void kernel_launch(void* const* d_in, const int* in_sizes, int n_in,
                              void* d_out, int out_size, void* d_ws, size_t ws_size,
                              hipStream_t stream) {
    const float* X  = (const float*)d_in[0];
    const float* Wq = (const float*)d_in[1];
    const float* bq = (const float*)d_in[2];
    const float* Wk = (const float*)d_in[3];
    const float* bk = (const float*)d_in[4];
    const float* Wv = (const float*)d_in[5];
    const float* bv = (const float*)d_in[6];
    float* out = (float*)d_out;

    char* ws = (char*)d_ws;
    const size_t EB = (size_t)BATCH * SEQ * SEQ * 2;     // 134,217,728
    const size_t XB = (size_t)BATCH * SEQ * HIDDEN * 2;  // 33,554,432
    const size_t WB = (size_t)HIDDEN * HIDDEN * 2;       // 2,097,152

    _Float16* E   = (_Float16*)ws;
    _Float16* Xh  = (_Float16*)ws;                       // aliases E head
    _Float16* Wqh = (_Float16*)(ws + XB);
    _Float16* Wkh = (_Float16*)(ws + XB + WB);
    _Float16* Wvh = (_Float16*)(ws + XB + 2 * WB);
    _Float16* Qh  = (_Float16*)(ws + EB);
    _Float16* Kh  = (_Float16*)(ws + EB + XB);
    _Float16* Vt  = (_Float16*)(ws + EB + 2 * XB);       // [B][H][S]
    float*    Lsum= (float*)   (ws + EB + 3 * XB);       // [B][S]

    // 1. casts
    cast_x_kernel<<<dim3(16384), dim3(256), 0, stream>>>(X, Xh);
    cast_w_kernel<<<dim3(1024, 1, 3), dim3(256), 0, stream>>>(
        Wq, Wk, Wv, Wqh, Wkh, Wvh);

    hipMemsetAsync(Lsum, 0, (size_t)BATCH * SEQ * sizeof(float), stream);

    // 2. fused QKV projection: [16384,1024] x [3072,1024]^T, 256^2 tiles
    gemm256_kernel<5, 32><<<dim3(768), dim3(512), 0, stream>>>(
        Xh, Wqh, Wkh, Wvh, bq, bk, bv, 0.f,
        nullptr, Qh, Kh, Vt, nullptr, nullptr);

    // 3. QK^T -> exp -> E (fp16) + row sums: 256^2 tiles, 2 blocks/CU
    const float alpha2 = (1.0f / 32.0f) * 1.4426950408889634f;  // /sqrt(H)*log2e
    gemm256_kernel<3, 32><<<dim3(256, 4), dim3(512), 0, stream>>>(
        Qh, Kh, nullptr, nullptr, nullptr, nullptr, nullptr, alpha2,
        E, nullptr, nullptr, nullptr, nullptr, Lsum);

    // 4. PV with 1/Lsum scaling: 256^2 tiles, NT=128
    gemm256_kernel<4, 128><<<dim3(64, 4), dim3(512), 0, stream>>>(
        E, Vt, nullptr, nullptr, nullptr, nullptr, nullptr, 0.f,
        nullptr, nullptr, nullptr, nullptr, out, Lsum);
}

// Round 10
// 518.272 us; speedup vs baseline: 1.1521x; 1.0012x over previous
//
#include <hip/hip_runtime.h>
#include <math.h>

#define HIDDEN 1024
#define SEQ    4096
#define BATCH  4

typedef _Float16 f16x8 __attribute__((ext_vector_type(8)));
typedef float    floatx4 __attribute__((ext_vector_type(4)));

// async 16B global->LDS copy (m97: width=16 emits global_load_lds_dwordx4)
__device__ inline void gld16(const void* g, void* l) {
    __builtin_amdgcn_global_load_lds(
        (const __attribute__((address_space(1))) unsigned int*)g,
        (__attribute__((address_space(3))) unsigned int*)l, 16, 0, 0);
}

// ===========================================================================
// Unified 256x256-tile GEMM, BK=32, 512 thr = 8 waves (2M x 4N), wave tile
// 128x64. Registers: 128 AGPR acc + ~112 VGPR = ~240 -> 2 waves/SIMD,
// 1 block/CU (reg-capped; LDS is free up to 160 KB).
//
// R7 structure: 3-buffer LDS (96 KB), depth-2 staging, read-ahead-1 frags,
// ONE barrier per tile, counted vmcnt(4), NO compile-time fences.
// Per tile t (bufs: c=t%3 frags already in regs, n=(t+1)%3, x=(t+2)%3):
//   stage A,B(t+2) -> buf x          // 4 gld16
//   s_waitcnt vmcnt(4)               // drains t+1's loads (2-tile lead);
//                                    // BEFORE barrier (per-wave counter,
//                                    // cooperative staging)
//   s_barrier; ""-asm memory fence   // fence keeps the RDs below barrier
//   MM0 (afA x bfX); MM1 (afB x bfX) // frags of t, read last tile; reg-only
//   RD afA,bfX,afB <- buf n          // 12 ds_read; WAR orders them after the
//                                    // consuming MFMAs issue; NO sched fences
//                                    // -> compiler interleaves reads into the
//                                    // MFMA stream: LDS pipe (~1150cy/CU/tile)
//                                    // runs UNDER MFMA (~1240cy) instead of
//                                    // serializing with it (the measured
//                                    // 35%-MfmaUtil disease of R1-R6).
// (NT-2) % 3 == 0 for NT=32 and NT=128 -> static 3-buffer rotation.
//
// MODE 5: fused QKV projection. A=Xh [16384,1024], B=W{q,k,v} [1024,1024].
//         grid 768 = 64 row x 12 col tiles, XCD-swizzled. which = col0>>10;
//         which<2 -> Qo/Ko[r*1024+cl]; which==2 -> Vt[(b*1024+cl)*4096+s].
// MODE 3: QK^T -> exp2 -> E fp16 + Lsum atomics. grid (256,4), NT=32.
// MODE 4: PV. A=E[b] (lda 4096), B=Vt[b] (ldb 4096), NT=128, grid (64,4).
//         out = acc / Lsum[row].
// ===========================================================================
template<int MODE, int NT>
__global__ __launch_bounds__(512, 2)
void gemm256_kernel(const _Float16* __restrict__ A,
                    const _Float16* __restrict__ Bq,
                    const _Float16* __restrict__ Bk,
                    const _Float16* __restrict__ Bv,
                    const float* __restrict__ bq,
                    const float* __restrict__ bk,
                    const float* __restrict__ bv,
                    float alpha,
                    _Float16* __restrict__ Eo,
                    _Float16* __restrict__ Qo,
                    _Float16* __restrict__ Ko,
                    _Float16* __restrict__ Vo,
                    float* __restrict__ Cf,
                    float* __restrict__ Lsum) {
    constexpr int LDAB = (MODE == 4) ? SEQ : HIDDEN;   // row stride, both ops
    __shared__ __align__(16) char smem[98304];
    char* const sA0 = smem;
    char* const sA1 = smem + 16384;
    char* const sA2 = smem + 32768;
    char* const sB0 = smem + 49152;
    char* const sB1 = smem + 65536;
    char* const sB2 = smem + 81920;

    const int tid  = threadIdx.x;
    const int lane = tid & 63;
    const int w    = tid >> 6;   // 0..7
    const int wm   = w & 1;      // 128-row half
    const int wn   = w >> 1;     // 0..3: 64-col group
    const int quad = lane >> 4;
    const int l16  = lane & 15;
    const int swz  = (l16 >> 1) & 3;

    int row0, col0, z = 0;
    if constexpr (MODE == 5) {
        // 768 blocks: xcd = n&7, 96 slots, 12 col-tiles fastest within XCD
        const int n = blockIdx.x, xcd = n & 7, slot = n >> 3;
        const int cc = slot % 12, rg = xcd + 8 * (slot / 12);  // rg 0..63
        row0 = rg * 256; col0 = cc * 256;
    } else if constexpr (MODE == 3) {
        z = blockIdx.y;
        const int bx = blockIdx.x, wgid = (bx & 7) * 32 + (bx >> 3);
        row0 = (wgid >> 4) * 256; col0 = (wgid & 15) * 256;
    } else {  // MODE 4
        z = blockIdx.y;
        const int n = blockIdx.x, xcd = n & 7, slot = n >> 3;  // slot 0..7
        const int cc = slot & 3, rg = xcd + 8 * (slot >> 2);   // rg 0..15
        row0 = rg * 256; col0 = cc * 256;
    }

    const _Float16* Abase;
    const _Float16* Bbase;
    int colbase = col0, which = 0;
    if constexpr (MODE == 5) {
        which = col0 >> 10; colbase = col0 & 1023;
        const _Float16* Bsrc = (which == 0) ? Bq : (which == 1) ? Bk : Bv;
        Abase = A + (size_t)row0 * HIDDEN;
        Bbase = Bsrc + (size_t)colbase * HIDDEN;
    } else if constexpr (MODE == 3) {
        Abase = A  + (size_t)z * SEQ * HIDDEN + (size_t)row0 * HIDDEN;
        Bbase = Bq + (size_t)z * SEQ * HIDDEN + (size_t)col0 * HIDDEN;
        Eo   += (size_t)z * SEQ * SEQ;
        Lsum += (size_t)z * SEQ;
    } else {
        Abase = A  + (size_t)z * SEQ * SEQ    + (size_t)row0 * SEQ;
        Bbase = Bq + (size_t)z * HIDDEN * SEQ + (size_t)col0 * SEQ;
        Cf   += (size_t)z * SEQ * HIDDEN;
        Lsum += (size_t)z * SEQ;
    }

    // per-thread staging chunks: a K-tile of A (or B) = 256 rows x 4 chunks
    // = 1024 chunks; 512 thr -> 2 gld16 each (dest = uniform + lane*16)
    const int n0 = tid, n1 = tid + 512;
    const int r0s = n0 >> 2, p0s = n0 & 3;
    const int r1s = n1 >> 2, p1s = n1 & 3;
    const int off0 = r0s * LDAB + (p0s ^ ((r0s >> 1) & 3)) * 8;  // pre-swizzled src
    const int off1 = r1s * LDAB + (p1s ^ ((r1s >> 1) & 3)) * 8;

    auto stage = [&](const _Float16* base, char* lh, int kt) {
        const int kb = kt * 32;
        gld16(base + off0 + kb, lh + n0 * 16);
        gld16(base + off1 + kb, lh + n1 * 16);
    };

    floatx4 acc[8][4];
    #pragma unroll
    for (int i = 0; i < 8; ++i)
        #pragma unroll
        for (int j = 0; j < 4; ++j) acc[i][j] = (floatx4){0.f, 0.f, 0.f, 0.f};

    f16x8 afA[4], afB[4], bfX[4];

#define RD_AF(DST, RH, PBUF)                                                  \
  { const f16x8* pAh = (const f16x8*)(PBUF);                                  \
    _Pragma("unroll")                                                         \
    for (int i = 0; i < 4; ++i)                                               \
      DST[i] = pAh[(wm * 128 + (RH) * 64 + i * 16 + l16) * 4 + (quad ^ swz)]; }

#define RD_BF(DST, PBUF)                                                      \
  { const f16x8* pBh = (const f16x8*)(PBUF);                                  \
    _Pragma("unroll")                                                         \
    for (int j = 0; j < 4; ++j)                                               \
      DST[j] = pBh[(wn * 64 + j * 16 + l16) * 4 + (quad ^ swz)]; }

#define MM(RH, AF, BF)                                                        \
  _Pragma("unroll")                                                           \
  for (int j = 0; j < 4; ++j)                                                 \
    _Pragma("unroll")                                                         \
    for (int i = 0; i < 4; ++i)                                               \
      acc[(RH) * 4 + i][j] = __builtin_amdgcn_mfma_f32_16x16x32_f16(          \
          AF[i], BF[j], acc[(RH) * 4 + i][j], 0, 0, 0);

// One tile: frags of tile T already in regs; stage T+2 -> (AX,BX);
// counted vmcnt; barrier (+compile-time fence so RDs stay below);
// MFMA on current frags; read T+1 frags from (AN,BN) into the SAME regs
// (WAR naturally orders reads after the consuming MFMAs issue).
#define QT(AN, BN, AX, BX, KT2, STG, W)                                       \
  { if (STG) { stage(Abase, AX, KT2); stage(Bbase, BX, KT2); }                \
    asm volatile("s_waitcnt vmcnt(" W ")" ::: "memory");                      \
    __builtin_amdgcn_s_barrier();                                             \
    asm volatile("" ::: "memory");                                            \
    MM(0, afA, bfX)                                                           \
    MM(1, afB, bfX)                                                           \
    RD_AF(afA, 0, AN)                                                         \
    RD_BF(bfX, BN)                                                            \
    RD_AF(afB, 1, AN) }

    // prologue: tiles 0,1 -> bufs 0,1; drain tile0's loads; prime frags
    stage(Abase, sA0, 0);
    stage(Bbase, sB0, 0);
    stage(Abase, sA1, 1);
    stage(Bbase, sB1, 1);
    asm volatile("s_waitcnt vmcnt(4)" ::: "memory");
    __builtin_amdgcn_s_barrier();
    asm volatile("" ::: "memory");
    RD_AF(afA, 0, sA0)
    RD_BF(bfX, sB0)
    RD_AF(afB, 1, sA0)

    // steady: (NT-2) iterations, statically 3-unrolled (30 | 126, both %3==0)
    for (int t = 0; t < NT - 2; t += 3) {
        QT(sA1, sB1, sA2, sB2, t + 2, 1, "4")   // tile t   : rd t+1<-b1, stg t+2->b2
        QT(sA2, sB2, sA0, sB0, t + 3, 1, "4")   // tile t+1 : rd t+2<-b2, stg t+3->b0
        QT(sA0, sB0, sA1, sB1, t + 4, 1, "4")   // tile t+2 : rd t+3<-b0, stg t+4->b1
    }
    // tile NT-2 (== 0 mod 3): no stage; drain tile NT-1's loads; rd NT-1<-b1
    QT(sA1, sB1, sA2, sB2, 0, 0, "0")
    // tile NT-1: compute only
    MM(0, afA, bfX)
    MM(1, afB, bfX)

#undef QT
#undef MM
#undef RD_BF
#undef RD_AF

    // ---- epilogue (C/D layout: col=lane&15, row=quad*4+reg) ----
    #pragma unroll
    for (int i = 0; i < 8; ++i) {
        const int r0 = row0 + wm * 128 + i * 16 + quad * 4;
        if constexpr (MODE == 3) {
            float rp[4] = {0.f, 0.f, 0.f, 0.f};
            #pragma unroll
            for (int j = 0; j < 4; ++j) {
                const int cl = col0 + wn * 64 + j * 16 + l16;
                #pragma unroll
                for (int reg = 0; reg < 4; ++reg) {
                    const float v = exp2f(alpha * acc[i][j][reg] - 5.770780163555856f);
                    const _Float16 vh = (_Float16)v;
                    Eo[(size_t)(r0 + reg) * SEQ + cl] = vh;
                    rp[reg] += (float)vh;
                }
            }
            #pragma unroll
            for (int off = 1; off < 16; off <<= 1)
                #pragma unroll
                for (int reg = 0; reg < 4; ++reg)
                    rp[reg] += __shfl_xor(rp[reg], off, 64);
            if (l16 == 0)
                #pragma unroll
                for (int reg = 0; reg < 4; ++reg)
                    atomicAdd(&Lsum[r0 + reg], rp[reg]);
        } else if constexpr (MODE == 5) {
            #pragma unroll
            for (int j = 0; j < 4; ++j) {
                const int cl = colbase + wn * 64 + j * 16 + l16;
                const float bcol = (which == 0 ? bq : which == 1 ? bk : bv)[cl];
                if (which < 2) {
                    _Float16* O = (which == 0) ? Qo : Ko;
                    #pragma unroll
                    for (int reg = 0; reg < 4; ++reg)
                        O[(size_t)(r0 + reg) * HIDDEN + cl] =
                            (_Float16)(acc[i][j][reg] + bcol);
                } else {
                    const int bb = r0 >> 12;
                    const int s  = r0 & 4095;
                    _Float16 tq[4];
                    #pragma unroll
                    for (int reg = 0; reg < 4; ++reg)
                        tq[reg] = (_Float16)(acc[i][j][reg] + bcol);
                    *(uint2*)&Vo[((size_t)bb * HIDDEN + cl) * SEQ + s] = *(const uint2*)tq;
                }
            }
        } else {  // MODE 4: PV, scale by 1/Lsum
            float linv[4];
            #pragma unroll
            for (int reg = 0; reg < 4; ++reg) linv[reg] = 1.0f / Lsum[r0 + reg];
            #pragma unroll
            for (int j = 0; j < 4; ++j) {
                const int cl = col0 + wn * 64 + j * 16 + l16;
                #pragma unroll
                for (int reg = 0; reg < 4; ++reg)
                    Cf[(size_t)(r0 + reg) * HIDDEN + cl] = acc[i][j][reg] * linv[reg];
            }
        }
    }
}

// ---------------------------------------------------------------------------
// fp32 -> fp16 casts
// ---------------------------------------------------------------------------
__global__ __launch_bounds__(256)
void cast_x_kernel(const float* __restrict__ in, _Float16* __restrict__ out) {
    const int i = blockIdx.x * 256 + threadIdx.x;
    const float4 x = ((const float4*)in)[i];
    _Float16 h[4] = {(_Float16)x.x, (_Float16)x.y, (_Float16)x.z, (_Float16)x.w};
    ((uint2*)out)[i] = *(const uint2*)h;
}

__global__ __launch_bounds__(256)
void cast_w_kernel(const float* __restrict__ w0, const float* __restrict__ w1,
                   const float* __restrict__ w2,
                   _Float16* __restrict__ o0, _Float16* __restrict__ o1,
                   _Float16* __restrict__ o2) {
    const float* in = (blockIdx.z == 0) ? w0 : (blockIdx.z == 1) ? w1 : w2;
    _Float16* out   = (blockIdx.z == 0) ? o0 : (blockIdx.z == 1) ? o1 : o2;
    const int i = blockIdx.x * 256 + threadIdx.x;
    const float4 x = ((const float4*)in)[i];
    _Float16 h[4] = {(_Float16)x.x, (_Float16)x.y, (_Float16)x.z, (_Float16)x.w};
    ((uint2*)out)[i] = *(const uint2*)h;
}

// ---------------------------------------------------------------------------
// ws layout (bytes), total ~235 MB:
//   [0, 134.2M) : E fp16 [B][S][S]  (head aliases Xh + W casts, dead by then)
//   then        : Qh 33.5M | Kh 33.5M | Vt [B][H][S] 33.5M | Lsum 64K
// ---------------------------------------------------------------------------
extern "C" void kernel_launch(void* const* d_in, const int* in_sizes, int n_in,
                              void* d_out, int out_size, void* d_ws, size_t ws_size,
                              hipStream_t stream) {
    const float* X  = (const float*)d_in[0];
    const float* Wq = (const float*)d_in[1];
    const float* bq = (const float*)d_in[2];
    const float* Wk = (const float*)d_in[3];
    const float* bk = (const float*)d_in[4];
    const float* Wv = (const float*)d_in[5];
    const float* bv = (const float*)d_in[6];
    float* out = (float*)d_out;

    char* ws = (char*)d_ws;
    const size_t EB = (size_t)BATCH * SEQ * SEQ * 2;     // 134,217,728
    const size_t XB = (size_t)BATCH * SEQ * HIDDEN * 2;  // 33,554,432
    const size_t WB = (size_t)HIDDEN * HIDDEN * 2;       // 2,097,152

    _Float16* E   = (_Float16*)ws;
    _Float16* Xh  = (_Float16*)ws;                       // aliases E head
    _Float16* Wqh = (_Float16*)(ws + XB);
    _Float16* Wkh = (_Float16*)(ws + XB + WB);
    _Float16* Wvh = (_Float16*)(ws + XB + 2 * WB);
    _Float16* Qh  = (_Float16*)(ws + EB);
    _Float16* Kh  = (_Float16*)(ws + EB + XB);
    _Float16* Vt  = (_Float16*)(ws + EB + 2 * XB);       // [B][H][S]
    float*    Lsum= (float*)   (ws + EB + 3 * XB);       // [B][S]

    // 1. casts
    cast_x_kernel<<<dim3(16384), dim3(256), 0, stream>>>(X, Xh);
    cast_w_kernel<<<dim3(1024, 1, 3), dim3(256), 0, stream>>>(
        Wq, Wk, Wv, Wqh, Wkh, Wvh);

    hipMemsetAsync(Lsum, 0, (size_t)BATCH * SEQ * sizeof(float), stream);

    // 2. fused QKV projection: [16384,1024] x [3072,1024]^T, 256^2 tiles
    gemm256_kernel<5, 32><<<dim3(768), dim3(512), 0, stream>>>(
        Xh, Wqh, Wkh, Wvh, bq, bk, bv, 0.f,
        nullptr, Qh, Kh, Vt, nullptr, nullptr);

    // 3. QK^T -> exp -> E (fp16) + row sums: 256^2 tiles, pipelined reads
    const float alpha2 = (1.0f / 32.0f) * 1.4426950408889634f;  // /sqrt(H)*log2e
    gemm256_kernel<3, 32><<<dim3(256, 4), dim3(512), 0, stream>>>(
        Qh, Kh, nullptr, nullptr, nullptr, nullptr, nullptr, alpha2,
        E, nullptr, nullptr, nullptr, nullptr, Lsum);

    // 4. PV with 1/Lsum scaling: 256^2 tiles, NT=128
    gemm256_kernel<4, 128><<<dim3(64, 4), dim3(512), 0, stream>>>(
        E, Vt, nullptr, nullptr, nullptr, nullptr, nullptr, 0.f,
        nullptr, nullptr, nullptr, nullptr, out, Lsum);
}